// Round 9
// baseline (54.177 us; speedup 1.0000x reference)
//
#include <hip/hip_runtime.h>

typedef __bf16 bf16x8 __attribute__((ext_vector_type(8)));
typedef float  f32x16 __attribute__((ext_vector_type(16)));
typedef unsigned int uint4v __attribute__((ext_vector_type(4)));

#define MFMA32(A, B, C) __builtin_amdgcn_mfma_f32_32x32x16_bf16((A), (B), (C), 0, 0, 0)

__device__ __forceinline__ bf16x8 load8_bf(const float* __restrict__ p, float scale) {
    const float4 a = *reinterpret_cast<const float4*>(p);
    const float4 b = *reinterpret_cast<const float4*>(p + 4);
    bf16x8 r;
    r[0] = (__bf16)(a.x * scale); r[1] = (__bf16)(a.y * scale);
    r[2] = (__bf16)(a.z * scale); r[3] = (__bf16)(a.w * scale);
    r[4] = (__bf16)(b.x * scale); r[5] = (__bf16)(b.y * scale);
    r[6] = (__bf16)(b.z * scale); r[7] = (__bf16)(b.w * scale);
    return r;
}

__device__ __forceinline__ unsigned pack2(float a, float b) {
    unsigned la = (unsigned)__builtin_bit_cast(unsigned short, (__bf16)a);
    unsigned lb = (unsigned)__builtin_bit_cast(unsigned short, (__bf16)b);
    return la | (lb << 16);
}

__device__ __forceinline__ void swap32(unsigned& a, unsigned& b) {
#if __has_builtin(__builtin_amdgcn_permlane32_swap)
    auto r = __builtin_amdgcn_permlane32_swap(a, b, false, false);
    a = r[0]; b = r[1];
#else
    asm("v_permlane32_swap_b32 %0, %1" : "+v"(a), "+v"(b));
#endif
}

// rearrange(D in C-layout) = A-fragments of D^T  (PROVEN R2..R8):
// input: lane holds D[r(e,hi)][col], r(e,hi)=(e&3)+8*(e>>2)+4*hi
// output: lane holds D^T[col][k]; f0: k=hi*8+q, f1: k=16+hi*8+q.
__device__ __forceinline__ void rearrange(const f32x16& a, bf16x8& f0, bf16x8& f1) {
    unsigned D0 = pack2(a[0], a[1]),   D1 = pack2(a[2], a[3]);
    unsigned D2 = pack2(a[4], a[5]),   D3 = pack2(a[6], a[7]);
    unsigned D4 = pack2(a[8], a[9]),   D5 = pack2(a[10], a[11]);
    unsigned D6 = pack2(a[12], a[13]), D7 = pack2(a[14], a[15]);
    swap32(D0, D2); swap32(D1, D3); swap32(D4, D6); swap32(D5, D7);
    f0 = __builtin_bit_cast(bf16x8, uint4v{D0, D1, D2, D3});
    f1 = __builtin_bit_cast(bf16x8, uint4v{D4, D5, D6, D7});
}

__device__ __forceinline__ void ld4(const float* __restrict__ p,
                                    float4& r0, float4& r1, float4& r2, float4& r3) {
    r0 = *reinterpret_cast<const float4*>(p);
    r1 = *reinterpret_cast<const float4*>(p + 4);
    r2 = *reinterpret_cast<const float4*>(p + 16);
    r3 = *reinterpret_cast<const float4*>(p + 20);
}

__device__ __forceinline__ void cvt8(const float4& a, const float4& b, bf16x8& f) {
    f[0] = (__bf16)a.x; f[1] = (__bf16)a.y; f[2] = (__bf16)a.z; f[3] = (__bf16)a.w;
    f[4] = (__bf16)b.x; f[5] = (__bf16)b.y; f[6] = (__bf16)b.z; f[7] = (__bf16)b.w;
}

// R8 math (NN/u precompute, 10 MFMAs/batch) + XCD-chunked swizzle (contiguous
// batch range per XCD -> L2 write-back aggregates consecutive 128-B segments)
// + prefetch depth 2 (8 KB outstanding per wave).
__global__ __launch_bounds__(256) void attn32(
    const float* __restrict__ x,
    const float* __restrict__ Wk, const float* __restrict__ bk,
    const float* __restrict__ Wq, const float* __restrict__ bq,
    const float* __restrict__ Wv, const float* __restrict__ bv,
    const float* __restrict__ Wp, const float* __restrict__ bp,
    float* __restrict__ out, int Btot)
{
    const int lane = threadIdx.x & 63;
    const int col  = lane & 31;
    const int hi   = lane >> 5;

    // XCD-chunked swizzle: hardware places block g on XCD g%8; remap so XCD k
    // owns the contiguous batch range [k*Btot/8, (k+1)*Btot/8).
    const unsigned g = blockIdx.x;
    const unsigned swz = (g & 7) * (gridDim.x >> 3) + (g >> 3);
    const int gw = (int)swz * 4 + (threadIdx.x >> 6);
    const int nw = gridDim.x * 4;
    if (gw >= Btot) return;

    // fold 1/sqrt(32)*log2(e) so softmax uses exp2 directly
    const float SC = 0.17677669529663687f * 1.4426950408889634f;

    const int wrow = col * 32 + hi * 8;

    // prologue prefetch of first two batches (overlaps all setup below)
    float4 A0, A1, A2, A3, B0, B1, B2, B3;
    ld4(x + (size_t)gw * 1024 + wrow, A0, A1, A2, A3);
    {
        const int b1 = gw + nw;
        if (b1 < Btot) ld4(x + (size_t)b1 * 1024 + wrow, B0, B1, B2, B3);
    }

    // row-loaded weights (as B-operands: B = W^T)
    const bf16x8 wv0 = load8_bf(Wv + wrow, 1.f), wv1 = load8_bf(Wv + wrow + 16, 1.f);
    const bf16x8 wp0 = load8_bf(Wp + wrow, 1.f), wp1 = load8_bf(Wp + wrow + 16, 1.f);

    // column-loaded Wk, Wq (setup only): lane holds W[k][col], k=hi*8+q (+16)
    bf16x8 wkc0, wkc1, wqc0, wqc1, bqb0, bqb1;
#pragma unroll
    for (int q = 0; q < 8; ++q) {
        wkc0[q] = (__bf16)Wk[(hi * 8 + q) * 32 + col];
        wkc1[q] = (__bf16)Wk[(16 + hi * 8 + q) * 32 + col];
        wqc0[q] = (__bf16)(SC * Wq[(hi * 8 + q) * 32 + col]);
        wqc1[q] = (__bf16)(SC * Wq[(16 + hi * 8 + q) * 32 + col]);
        bqb0[q] = (__bf16)(SC * bq[hi * 8 + q]);
        bqb1[q] = (__bf16)(SC * bq[16 + hi * 8 + q]);
    }

    f32x16 acc;
#pragma unroll
    for (int e = 0; e < 16; ++e) acc[e] = 0.f;

    // NN^T = (SC*Wq)^T * Wk
    acc = MFMA32(wqc0, wkc0, acc);
    acc = MFMA32(wqc1, wkc1, acc);
    bf16x8 nA0, nA1; rearrange(acc, nA0, nA1);  // A-frags of NN

    // u[e] = SC*(Wk^T bq)[r(e,hi)]  -> keep packed as bf16 pairs (8 regs)
#pragma unroll
    for (int e = 0; e < 16; ++e) acc[e] = 0.f;
    acc = MFMA32(wkc0, bqb0, acc);
    acc = MFMA32(wkc1, bqb1, acc);
    unsigned up[8];
#pragma unroll
    for (int q = 0; q < 8; ++q) up[q] = pack2(acc[2 * q], acc[2 * q + 1]);

    const float bvv = bv[col];
    const float bpv = bp[col];

    for (int b = gw; b < Btot; b += nw) {
        bf16x8 xa0, xa1;   // lane holds X[col][k]; as A: X, as B: X^T
        cvt8(A0, A1, xa0);
        cvt8(A2, A3, xa1);
        // rotate prefetch pipeline: consume A, shift B->A, issue depth-2 load
        A0 = B0; A1 = B1; A2 = B2; A3 = B3;
        const int nb2 = b + 2 * nw;
        if (nb2 < Btot) ld4(x + (size_t)nb2 * 1024 + wrow, B0, B1, B2, B3);

        // V = X*Wv^T + 1*bv^T
#pragma unroll
        for (int e = 0; e < 16; ++e) acc[e] = bvv;
        acc = MFMA32(xa0, wv0, acc);
        acc = MFMA32(xa1, wv1, acc);
        bf16x8 vT0, vT1; rearrange(acc, vT0, vT1);  // A-frags of V^T

        // R^T = V^T * Wp^T
#pragma unroll
        for (int e = 0; e < 16; ++e) acc[e] = 0.f;
        acc = MFMA32(vT0, wp0, acc);
        acc = MFMA32(vT1, wp1, acc);
        bf16x8 rB0, rB1; rearrange(acc, rB0, rB1);  // as B: R^T

        // H = NN*X^T + u*1^T
#pragma unroll
        for (int q = 0; q < 8; ++q) {
            acc[2 * q]     = __builtin_bit_cast(float, up[q] << 16);
            acc[2 * q + 1] = __builtin_bit_cast(float, up[q] & 0xffff0000u);
        }
        acc = MFMA32(nA0, xa0, acc);
        acc = MFMA32(nA1, xa1, acc);
        bf16x8 hb0, hb1; rearrange(acc, hb0, hb1);  // as B: H

        // S^T(core) = X*H : col=lane=query t, row=key t'
        f32x16 s;
#pragma unroll
        for (int e = 0; e < 16; ++e) s[e] = 0.f;
        s = MFMA32(xa0, hb0, s);
        s = MFMA32(xa1, hb1, s);

        // causal mask + max-subtracted softmax (proven; exp2, SC pre-folded)
        f32x16 pv;
        {
            float sv[16];
            float m = -3.0e38f;
#pragma unroll
            for (int e = 0; e < 16; ++e) {
                const int j = (e & 3) + 8 * (e >> 2) + 4 * hi;
                sv[e] = (j <= col) ? s[e] : -__builtin_inff();
                m = fmaxf(m, sv[e]);
            }
            m = fmaxf(m, __shfl_xor(m, 32));
            float pe[16];
            float sum = 0.f;
#pragma unroll
            for (int e = 0; e < 16; ++e) { pe[e] = __builtin_amdgcn_exp2f(sv[e] - m); sum += pe[e]; }
            sum += __shfl_xor(sum, 32);
            const float inv = __builtin_amdgcn_rcpf(sum);
#pragma unroll
            for (int e = 0; e < 16; ++e) pv[e] = pe[e] * inv;
        }
        bf16x8 pa0, pa1; rearrange(pv, pa0, pa1);  // A-frags of P

        // out = P*R^T + 1*bp^T
        f32x16 o;
#pragma unroll
        for (int e = 0; e < 16; ++e) o[e] = bpv;
        o = MFMA32(pa0, rB0, o);
        o = MFMA32(pa1, rB1, o);

        // out flat [T, B, C]: element r*2^20 + b*32 + col (proven)
        float* const ob = out + (size_t)b * 32 + col;
#pragma unroll
        for (int e = 0; e < 16; ++e) {
            const int r = (e & 3) + 8 * (e >> 2) + 4 * hi;
            __builtin_nontemporal_store(o[e], ob + ((size_t)r << 20));
        }
    }
}

extern "C" void kernel_launch(void* const* d_in, const int* in_sizes, int n_in,
                              void* d_out, int out_size, void* d_ws, size_t ws_size,
                              hipStream_t stream) {
    const float* x  = (const float*)d_in[0];
    const float* Wk = (const float*)d_in[1];
    const float* bk = (const float*)d_in[2];
    const float* Wq = (const float*)d_in[3];
    const float* bq = (const float*)d_in[4];
    const float* Wv = (const float*)d_in[5];
    const float* bv = (const float*)d_in[6];
    const float* Wp = (const float*)d_in[7];
    const float* bp = (const float*)d_in[8];
    float* out = (float*)d_out;

    const int Btot = in_sizes[0] / 1024;  // [B,32,32] fp32
    dim3 grid(2048), block(256);          // 2048 % 8 == 0 for the swizzle
    hipLaunchKernelGGL(attn32, grid, block, 0, stream,
                       x, Wk, bk, Wq, bq, Wv, bv, Wp, bp, out, Btot);
}

// Round 10
// 49.046 us; speedup vs baseline: 1.1046x; 1.1046x over previous
//
#include <hip/hip_runtime.h>

typedef __bf16 bf16x8 __attribute__((ext_vector_type(8)));
typedef float  f32x16 __attribute__((ext_vector_type(16)));
typedef unsigned int uint4v __attribute__((ext_vector_type(4)));

#define MFMA32(A, B, C) __builtin_amdgcn_mfma_f32_32x32x16_bf16((A), (B), (C), 0, 0, 0)

__device__ __forceinline__ bf16x8 load8_bf(const float* __restrict__ p, float scale) {
    const float4 a = *reinterpret_cast<const float4*>(p);
    const float4 b = *reinterpret_cast<const float4*>(p + 4);
    bf16x8 r;
    r[0] = (__bf16)(a.x * scale); r[1] = (__bf16)(a.y * scale);
    r[2] = (__bf16)(a.z * scale); r[3] = (__bf16)(a.w * scale);
    r[4] = (__bf16)(b.x * scale); r[5] = (__bf16)(b.y * scale);
    r[6] = (__bf16)(b.z * scale); r[7] = (__bf16)(b.w * scale);
    return r;
}

__device__ __forceinline__ unsigned pack2(float a, float b) {
    unsigned la = (unsigned)__builtin_bit_cast(unsigned short, (__bf16)a);
    unsigned lb = (unsigned)__builtin_bit_cast(unsigned short, (__bf16)b);
    return la | (lb << 16);
}

__device__ __forceinline__ void swap32(unsigned& a, unsigned& b) {
#if __has_builtin(__builtin_amdgcn_permlane32_swap)
    auto r = __builtin_amdgcn_permlane32_swap(a, b, false, false);
    a = r[0]; b = r[1];
#else
    asm("v_permlane32_swap_b32 %0, %1" : "+v"(a), "+v"(b));
#endif
}

// rearrange(D in C-layout) = A-fragments of D^T  (PROVEN R2..R9)
__device__ __forceinline__ void rearrange(const f32x16& a, bf16x8& f0, bf16x8& f1) {
    unsigned D0 = pack2(a[0], a[1]),   D1 = pack2(a[2], a[3]);
    unsigned D2 = pack2(a[4], a[5]),   D3 = pack2(a[6], a[7]);
    unsigned D4 = pack2(a[8], a[9]),   D5 = pack2(a[10], a[11]);
    unsigned D6 = pack2(a[12], a[13]), D7 = pack2(a[14], a[15]);
    swap32(D0, D2); swap32(D1, D3); swap32(D4, D6); swap32(D5, D7);
    f0 = __builtin_bit_cast(bf16x8, uint4v{D0, D1, D2, D3});
    f1 = __builtin_bit_cast(bf16x8, uint4v{D4, D5, D6, D7});
}

__device__ __forceinline__ void ld4(const float* __restrict__ p,
                                    float4& r0, float4& r1, float4& r2, float4& r3) {
    r0 = *reinterpret_cast<const float4*>(p);
    r1 = *reinterpret_cast<const float4*>(p + 4);
    r2 = *reinterpret_cast<const float4*>(p + 16);
    r3 = *reinterpret_cast<const float4*>(p + 20);
}

__device__ __forceinline__ void cvt8(const float4& a, const float4& b, bf16x8& f) {
    f[0] = (__bf16)a.x; f[1] = (__bf16)a.y; f[2] = (__bf16)a.z; f[3] = (__bf16)a.w;
    f[4] = (__bf16)b.x; f[5] = (__bf16)b.y; f[6] = (__bf16)b.z; f[7] = (__bf16)b.w;
}

// R8 math (NN/u precompute, 10 MFMAs/batch), TWO independent batch streams per
// loop iteration (ILP x2 in the latency-bound regime), loop+prefetch chassis.
__global__ __launch_bounds__(256) void attn32(
    const float* __restrict__ x,
    const float* __restrict__ Wk, const float* __restrict__ bk,
    const float* __restrict__ Wq, const float* __restrict__ bq,
    const float* __restrict__ Wv, const float* __restrict__ bv,
    const float* __restrict__ Wp, const float* __restrict__ bp,
    float* __restrict__ out, int Btot)
{
    const int lane = threadIdx.x & 63;
    const int col  = lane & 31;
    const int hi   = lane >> 5;

    const int nwave = gridDim.x * 4;            // waves in grid
    const int half  = Btot >> 1;                // stream B handles b + half
    const int gw    = blockIdx.x * 4 + (threadIdx.x >> 6);
    if (gw >= half) return;

    const float SC = 0.17677669529663687f * 1.4426950408889634f;
    const int wrow = col * 32 + hi * 8;

    // prologue prefetch: first batch of each stream (overlaps setup)
    float4 A0, A1, A2, A3, B0, B1, B2, B3;
    ld4(x + (size_t)gw * 1024 + wrow, A0, A1, A2, A3);
    ld4(x + (size_t)(gw + half) * 1024 + wrow, B0, B1, B2, B3);

    // row-loaded weights (as B-operands: B = W^T)
    const bf16x8 wv0 = load8_bf(Wv + wrow, 1.f), wv1 = load8_bf(Wv + wrow + 16, 1.f);
    const bf16x8 wp0 = load8_bf(Wp + wrow, 1.f), wp1 = load8_bf(Wp + wrow + 16, 1.f);

    // column-loaded Wk, Wq (setup only)
    bf16x8 wkc0, wkc1, wqc0, wqc1, bqb0, bqb1;
#pragma unroll
    for (int q = 0; q < 8; ++q) {
        wkc0[q] = (__bf16)Wk[(hi * 8 + q) * 32 + col];
        wkc1[q] = (__bf16)Wk[(16 + hi * 8 + q) * 32 + col];
        wqc0[q] = (__bf16)(SC * Wq[(hi * 8 + q) * 32 + col]);
        wqc1[q] = (__bf16)(SC * Wq[(16 + hi * 8 + q) * 32 + col]);
        bqb0[q] = (__bf16)(SC * bq[hi * 8 + q]);
        bqb1[q] = (__bf16)(SC * bq[16 + hi * 8 + q]);
    }

    f32x16 t;
#pragma unroll
    for (int e = 0; e < 16; ++e) t[e] = 0.f;
    // NN^T = (SC*Wq)^T * Wk
    t = MFMA32(wqc0, wkc0, t);
    t = MFMA32(wqc1, wkc1, t);
    bf16x8 nA0, nA1; rearrange(t, nA0, nA1);
    // u[e] = SC*(Wk^T bq)[r(e,hi)] packed bf16
#pragma unroll
    for (int e = 0; e < 16; ++e) t[e] = 0.f;
    t = MFMA32(wkc0, bqb0, t);
    t = MFMA32(wkc1, bqb1, t);
    unsigned up[8];
#pragma unroll
    for (int q = 0; q < 8; ++q) up[q] = pack2(t[2 * q], t[2 * q + 1]);

    const float bvv = bv[col];
    const float bpv = bp[col];

    for (int b = gw; b < half; b += nwave) {
        bf16x8 xaA0, xaA1, xaB0, xaB1;
        cvt8(A0, A1, xaA0); cvt8(A2, A3, xaA1);
        cvt8(B0, B1, xaB0); cvt8(B2, B3, xaB1);
        const int nb = b + nwave;
        if (nb < half) {
            ld4(x + (size_t)nb * 1024 + wrow, A0, A1, A2, A3);
            ld4(x + (size_t)(nb + half) * 1024 + wrow, B0, B1, B2, B3);
        }

        f32x16 aA, aB;

        // V = X*Wv^T + 1*bv^T
#pragma unroll
        for (int e = 0; e < 16; ++e) { aA[e] = bvv; aB[e] = bvv; }
        aA = MFMA32(xaA0, wv0, aA); aA = MFMA32(xaA1, wv1, aA);
        aB = MFMA32(xaB0, wv0, aB); aB = MFMA32(xaB1, wv1, aB);
        bf16x8 vTA0, vTA1, vTB0, vTB1;
        rearrange(aA, vTA0, vTA1);
        rearrange(aB, vTB0, vTB1);

        // R^T = V^T * Wp^T
#pragma unroll
        for (int e = 0; e < 16; ++e) { aA[e] = 0.f; aB[e] = 0.f; }
        aA = MFMA32(vTA0, wp0, aA); aA = MFMA32(vTA1, wp1, aA);
        aB = MFMA32(vTB0, wp0, aB); aB = MFMA32(vTB1, wp1, aB);
        bf16x8 rBA0, rBA1, rBB0, rBB1;
        rearrange(aA, rBA0, rBA1);
        rearrange(aB, rBB0, rBB1);

        // H = NN*X^T + u*1^T
#pragma unroll
        for (int q = 0; q < 8; ++q) {
            const float lo = __builtin_bit_cast(float, up[q] << 16);
            const float hv = __builtin_bit_cast(float, up[q] & 0xffff0000u);
            aA[2 * q] = lo; aA[2 * q + 1] = hv;
            aB[2 * q] = lo; aB[2 * q + 1] = hv;
        }
        aA = MFMA32(nA0, xaA0, aA); aA = MFMA32(nA1, xaA1, aA);
        aB = MFMA32(nA0, xaB0, aB); aB = MFMA32(nA1, xaB1, aB);
        bf16x8 hbA0, hbA1, hbB0, hbB1;
        rearrange(aA, hbA0, hbA1);
        rearrange(aB, hbB0, hbB1);

        // S^T(core) = X*H
        f32x16 sA, sB;
#pragma unroll
        for (int e = 0; e < 16; ++e) { sA[e] = 0.f; sB[e] = 0.f; }
        sA = MFMA32(xaA0, hbA0, sA); sA = MFMA32(xaA1, hbA1, sA);
        sB = MFMA32(xaB0, hbB0, sB); sB = MFMA32(xaB1, hbB1, sB);

        // causal mask + max-subtracted softmax, both streams interleaved
        f32x16 pvA, pvB;
        {
            float svA[16], svB[16];
            float mA = -3.0e38f, mB = -3.0e38f;
#pragma unroll
            for (int e = 0; e < 16; ++e) {
                const int j = (e & 3) + 8 * (e >> 2) + 4 * hi;
                svA[e] = (j <= col) ? sA[e] : -__builtin_inff();
                svB[e] = (j <= col) ? sB[e] : -__builtin_inff();
                mA = fmaxf(mA, svA[e]);
                mB = fmaxf(mB, svB[e]);
            }
            mA = fmaxf(mA, __shfl_xor(mA, 32));
            mB = fmaxf(mB, __shfl_xor(mB, 32));
            float sumA = 0.f, sumB = 0.f;
#pragma unroll
            for (int e = 0; e < 16; ++e) {
                svA[e] = __builtin_amdgcn_exp2f(svA[e] - mA); sumA += svA[e];
                svB[e] = __builtin_amdgcn_exp2f(svB[e] - mB); sumB += svB[e];
            }
            sumA += __shfl_xor(sumA, 32);
            sumB += __shfl_xor(sumB, 32);
            const float invA = __builtin_amdgcn_rcpf(sumA);
            const float invB = __builtin_amdgcn_rcpf(sumB);
#pragma unroll
            for (int e = 0; e < 16; ++e) { pvA[e] = svA[e] * invA; pvB[e] = svB[e] * invB; }
        }
        bf16x8 paA0, paA1, paB0, paB1;
        rearrange(pvA, paA0, paA1);
        rearrange(pvB, paB0, paB1);

        // out = P*R^T + 1*bp^T
        f32x16 oA, oB;
#pragma unroll
        for (int e = 0; e < 16; ++e) { oA[e] = bpv; oB[e] = bpv; }
        oA = MFMA32(paA0, rBA0, oA); oA = MFMA32(paA1, rBA1, oA);
        oB = MFMA32(paB0, rBB0, oB); oB = MFMA32(paB1, rBB1, oB);

        // out flat [T, B, C]: element r*2^20 + b*32 + col (proven)
        float* const obA = out + (size_t)b * 32 + col;
        float* const obB = out + (size_t)(b + half) * 32 + col;
#pragma unroll
        for (int e = 0; e < 16; ++e) {
            const int r = (e & 3) + 8 * (e >> 2) + 4 * hi;
            __builtin_nontemporal_store(oA[e], obA + ((size_t)r << 20));
            __builtin_nontemporal_store(oB[e], obB + ((size_t)r << 20));
        }
    }
}

extern "C" void kernel_launch(void* const* d_in, const int* in_sizes, int n_in,
                              void* d_out, int out_size, void* d_ws, size_t ws_size,
                              hipStream_t stream) {
    const float* x  = (const float*)d_in[0];
    const float* Wk = (const float*)d_in[1];
    const float* bk = (const float*)d_in[2];
    const float* Wq = (const float*)d_in[3];
    const float* bq = (const float*)d_in[4];
    const float* Wv = (const float*)d_in[5];
    const float* bv = (const float*)d_in[6];
    const float* Wp = (const float*)d_in[7];
    const float* bp = (const float*)d_in[8];
    float* out = (float*)d_out;

    const int Btot = in_sizes[0] / 1024;  // [B,32,32] fp32; even (32768)
    // 1024 blocks x 4 waves x 2 streams = 8192 batches/iter -> 4 iterations
    dim3 grid(1024), block(256);
    hipLaunchKernelGGL(attn32, grid, block, 0, stream,
                       x, Wk, bk, Wq, bq, Wv, bv, Wp, bp, out, Btot);
}

// Round 12
// 49.011 us; speedup vs baseline: 1.1054x; 1.0007x over previous
//
#include <hip/hip_runtime.h>

typedef __bf16 bf16x8 __attribute__((ext_vector_type(8)));
typedef float  f32x16 __attribute__((ext_vector_type(16)));
typedef unsigned int uint4v __attribute__((ext_vector_type(4)));

#define MFMA32(A, B, C) __builtin_amdgcn_mfma_f32_32x32x16_bf16((A), (B), (C), 0, 0, 0)

__device__ __forceinline__ bf16x8 load8_bf(const float* __restrict__ p, float scale) {
    const float4 a = *reinterpret_cast<const float4*>(p);
    const float4 b = *reinterpret_cast<const float4*>(p + 4);
    bf16x8 r;
    r[0] = (__bf16)(a.x * scale); r[1] = (__bf16)(a.y * scale);
    r[2] = (__bf16)(a.z * scale); r[3] = (__bf16)(a.w * scale);
    r[4] = (__bf16)(b.x * scale); r[5] = (__bf16)(b.y * scale);
    r[6] = (__bf16)(b.z * scale); r[7] = (__bf16)(b.w * scale);
    return r;
}

__device__ __forceinline__ unsigned pack2(float a, float b) {
    unsigned la = (unsigned)__builtin_bit_cast(unsigned short, (__bf16)a);
    unsigned lb = (unsigned)__builtin_bit_cast(unsigned short, (__bf16)b);
    return la | (lb << 16);
}

__device__ __forceinline__ void swap32(unsigned& a, unsigned& b) {
#if __has_builtin(__builtin_amdgcn_permlane32_swap)
    auto r = __builtin_amdgcn_permlane32_swap(a, b, false, false);
    a = r[0]; b = r[1];
#else
    asm("v_permlane32_swap_b32 %0, %1" : "+v"(a), "+v"(b));
#endif
}

// rearrange(D in C-layout) = A-fragments of D^T  (PROVEN R2..R10)
__device__ __forceinline__ void rearrange(const f32x16& a, bf16x8& f0, bf16x8& f1) {
    unsigned D0 = pack2(a[0], a[1]),   D1 = pack2(a[2], a[3]);
    unsigned D2 = pack2(a[4], a[5]),   D3 = pack2(a[6], a[7]);
    unsigned D4 = pack2(a[8], a[9]),   D5 = pack2(a[10], a[11]);
    unsigned D6 = pack2(a[12], a[13]), D7 = pack2(a[14], a[15]);
    swap32(D0, D2); swap32(D1, D3); swap32(D4, D6); swap32(D5, D7);
    f0 = __builtin_bit_cast(bf16x8, uint4v{D0, D1, D2, D3});
    f1 = __builtin_bit_cast(bf16x8, uint4v{D4, D5, D6, D7});
}

__device__ __forceinline__ void ld4(const float* __restrict__ p,
                                    float4& r0, float4& r1, float4& r2, float4& r3) {
    r0 = *reinterpret_cast<const float4*>(p);
    r1 = *reinterpret_cast<const float4*>(p + 4);
    r2 = *reinterpret_cast<const float4*>(p + 16);
    r3 = *reinterpret_cast<const float4*>(p + 20);
}

__device__ __forceinline__ void cvt8(const float4& a, const float4& b, bf16x8& f) {
    f[0] = (__bf16)a.x; f[1] = (__bf16)a.y; f[2] = (__bf16)a.z; f[3] = (__bf16)a.w;
    f[4] = (__bf16)b.x; f[5] = (__bf16)b.y; f[6] = (__bf16)b.z; f[7] = (__bf16)b.w;
}

// R8 math (NN/u precompute, 10 MFMAs/batch), TWO independent batch streams per
// loop iteration (ILP x2 in the latency-bound regime), loop+prefetch chassis.
// == R10 verbatim (proven pass, 49.0 us). R11's setprio/no-max deltas reverted:
// they were timing-null and one caused replay-order-dependent divergence.
__global__ __launch_bounds__(256) void attn32(
    const float* __restrict__ x,
    const float* __restrict__ Wk, const float* __restrict__ bk,
    const float* __restrict__ Wq, const float* __restrict__ bq,
    const float* __restrict__ Wv, const float* __restrict__ bv,
    const float* __restrict__ Wp, const float* __restrict__ bp,
    float* __restrict__ out, int Btot)
{
    const int lane = threadIdx.x & 63;
    const int col  = lane & 31;
    const int hi   = lane >> 5;

    const int nwave = gridDim.x * 4;            // waves in grid
    const int half  = Btot >> 1;                // stream B handles b + half
    const int gw    = blockIdx.x * 4 + (threadIdx.x >> 6);
    if (gw >= half) return;

    const float SC = 0.17677669529663687f * 1.4426950408889634f;
    const int wrow = col * 32 + hi * 8;

    // prologue prefetch: first batch of each stream (overlaps setup)
    float4 A0, A1, A2, A3, B0, B1, B2, B3;
    ld4(x + (size_t)gw * 1024 + wrow, A0, A1, A2, A3);
    ld4(x + (size_t)(gw + half) * 1024 + wrow, B0, B1, B2, B3);

    // row-loaded weights (as B-operands: B = W^T)
    const bf16x8 wv0 = load8_bf(Wv + wrow, 1.f), wv1 = load8_bf(Wv + wrow + 16, 1.f);
    const bf16x8 wp0 = load8_bf(Wp + wrow, 1.f), wp1 = load8_bf(Wp + wrow + 16, 1.f);

    // column-loaded Wk, Wq (setup only)
    bf16x8 wkc0, wkc1, wqc0, wqc1, bqb0, bqb1;
#pragma unroll
    for (int q = 0; q < 8; ++q) {
        wkc0[q] = (__bf16)Wk[(hi * 8 + q) * 32 + col];
        wkc1[q] = (__bf16)Wk[(16 + hi * 8 + q) * 32 + col];
        wqc0[q] = (__bf16)(SC * Wq[(hi * 8 + q) * 32 + col]);
        wqc1[q] = (__bf16)(SC * Wq[(16 + hi * 8 + q) * 32 + col]);
        bqb0[q] = (__bf16)(SC * bq[hi * 8 + q]);
        bqb1[q] = (__bf16)(SC * bq[16 + hi * 8 + q]);
    }

    f32x16 t;
#pragma unroll
    for (int e = 0; e < 16; ++e) t[e] = 0.f;
    // NN^T = (SC*Wq)^T * Wk
    t = MFMA32(wqc0, wkc0, t);
    t = MFMA32(wqc1, wkc1, t);
    bf16x8 nA0, nA1; rearrange(t, nA0, nA1);
    // u[e] = SC*(Wk^T bq)[r(e,hi)] packed bf16
#pragma unroll
    for (int e = 0; e < 16; ++e) t[e] = 0.f;
    t = MFMA32(wkc0, bqb0, t);
    t = MFMA32(wkc1, bqb1, t);
    unsigned up[8];
#pragma unroll
    for (int q = 0; q < 8; ++q) up[q] = pack2(t[2 * q], t[2 * q + 1]);

    const float bvv = bv[col];
    const float bpv = bp[col];

    for (int b = gw; b < half; b += nwave) {
        bf16x8 xaA0, xaA1, xaB0, xaB1;
        cvt8(A0, A1, xaA0); cvt8(A2, A3, xaA1);
        cvt8(B0, B1, xaB0); cvt8(B2, B3, xaB1);
        const int nb = b + nwave;
        if (nb < half) {
            ld4(x + (size_t)nb * 1024 + wrow, A0, A1, A2, A3);
            ld4(x + (size_t)(nb + half) * 1024 + wrow, B0, B1, B2, B3);
        }

        f32x16 aA, aB;

        // V = X*Wv^T + 1*bv^T
#pragma unroll
        for (int e = 0; e < 16; ++e) { aA[e] = bvv; aB[e] = bvv; }
        aA = MFMA32(xaA0, wv0, aA); aA = MFMA32(xaA1, wv1, aA);
        aB = MFMA32(xaB0, wv0, aB); aB = MFMA32(xaB1, wv1, aB);
        bf16x8 vTA0, vTA1, vTB0, vTB1;
        rearrange(aA, vTA0, vTA1);
        rearrange(aB, vTB0, vTB1);

        // R^T = V^T * Wp^T
#pragma unroll
        for (int e = 0; e < 16; ++e) { aA[e] = 0.f; aB[e] = 0.f; }
        aA = MFMA32(vTA0, wp0, aA); aA = MFMA32(vTA1, wp1, aA);
        aB = MFMA32(vTB0, wp0, aB); aB = MFMA32(vTB1, wp1, aB);
        bf16x8 rBA0, rBA1, rBB0, rBB1;
        rearrange(aA, rBA0, rBA1);
        rearrange(aB, rBB0, rBB1);

        // H = NN*X^T + u*1^T
#pragma unroll
        for (int q = 0; q < 8; ++q) {
            const float lo = __builtin_bit_cast(float, up[q] << 16);
            const float hv = __builtin_bit_cast(float, up[q] & 0xffff0000u);
            aA[2 * q] = lo; aA[2 * q + 1] = hv;
            aB[2 * q] = lo; aB[2 * q + 1] = hv;
        }
        aA = MFMA32(nA0, xaA0, aA); aA = MFMA32(nA1, xaA1, aA);
        aB = MFMA32(nA0, xaB0, aB); aB = MFMA32(nA1, xaB1, aB);
        bf16x8 hbA0, hbA1, hbB0, hbB1;
        rearrange(aA, hbA0, hbA1);
        rearrange(aB, hbB0, hbB1);

        // S^T(core) = X*H
        f32x16 sA, sB;
#pragma unroll
        for (int e = 0; e < 16; ++e) { sA[e] = 0.f; sB[e] = 0.f; }
        sA = MFMA32(xaA0, hbA0, sA); sA = MFMA32(xaA1, hbA1, sA);
        sB = MFMA32(xaB0, hbB0, sB); sB = MFMA32(xaB1, hbB1, sB);

        // causal mask + max-subtracted softmax, both streams interleaved
        f32x16 pvA, pvB;
        {
            float svA[16], svB[16];
            float mA = -3.0e38f, mB = -3.0e38f;
#pragma unroll
            for (int e = 0; e < 16; ++e) {
                const int j = (e & 3) + 8 * (e >> 2) + 4 * hi;
                svA[e] = (j <= col) ? sA[e] : -__builtin_inff();
                svB[e] = (j <= col) ? sB[e] : -__builtin_inff();
                mA = fmaxf(mA, svA[e]);
                mB = fmaxf(mB, svB[e]);
            }
            mA = fmaxf(mA, __shfl_xor(mA, 32));
            mB = fmaxf(mB, __shfl_xor(mB, 32));
            float sumA = 0.f, sumB = 0.f;
#pragma unroll
            for (int e = 0; e < 16; ++e) {
                svA[e] = __builtin_amdgcn_exp2f(svA[e] - mA); sumA += svA[e];
                svB[e] = __builtin_amdgcn_exp2f(svB[e] - mB); sumB += svB[e];
            }
            sumA += __shfl_xor(sumA, 32);
            sumB += __shfl_xor(sumB, 32);
            const float invA = __builtin_amdgcn_rcpf(sumA);
            const float invB = __builtin_amdgcn_rcpf(sumB);
#pragma unroll
            for (int e = 0; e < 16; ++e) { pvA[e] = svA[e] * invA; pvB[e] = svB[e] * invB; }
        }
        bf16x8 paA0, paA1, paB0, paB1;
        rearrange(pvA, paA0, paA1);
        rearrange(pvB, paB0, paB1);

        // out = P*R^T + 1*bp^T
        f32x16 oA, oB;
#pragma unroll
        for (int e = 0; e < 16; ++e) { oA[e] = bpv; oB[e] = bpv; }
        oA = MFMA32(paA0, rBA0, oA); oA = MFMA32(paA1, rBA1, oA);
        oB = MFMA32(paB0, rBB0, oB); oB = MFMA32(paB1, rBB1, oB);

        // out flat [T, B, C]: element r*2^20 + b*32 + col (proven)
        float* const obA = out + (size_t)b * 32 + col;
        float* const obB = out + (size_t)(b + half) * 32 + col;
#pragma unroll
        for (int e = 0; e < 16; ++e) {
            const int r = (e & 3) + 8 * (e >> 2) + 4 * hi;
            __builtin_nontemporal_store(oA[e], obA + ((size_t)r << 20));
            __builtin_nontemporal_store(oB[e], obB + ((size_t)r << 20));
        }
    }
}

extern "C" void kernel_launch(void* const* d_in, const int* in_sizes, int n_in,
                              void* d_out, int out_size, void* d_ws, size_t ws_size,
                              hipStream_t stream) {
    const float* x  = (const float*)d_in[0];
    const float* Wk = (const float*)d_in[1];
    const float* bk = (const float*)d_in[2];
    const float* Wq = (const float*)d_in[3];
    const float* bq = (const float*)d_in[4];
    const float* Wv = (const float*)d_in[5];
    const float* bv = (const float*)d_in[6];
    const float* Wp = (const float*)d_in[7];
    const float* bp = (const float*)d_in[8];
    float* out = (float*)d_out;

    const int Btot = in_sizes[0] / 1024;  // [B,32,32] fp32; even (32768)
    // 1024 blocks x 4 waves x 2 streams = 8192 batches/iter -> 4 iterations
    dim3 grid(1024), block(256);
    hipLaunchKernelGGL(attn32, grid, block, 0, stream,
                       x, Wk, bk, Wq, bq, Wv, bv, Wp, bp, out, Btot);
}